// Round 2
// baseline (1850.510 us; speedup 1.0000x reference)
//
#include <hip/hip_runtime.h>

// ---------------------------------------------------------------------------
// NaryCompUSchema: embed -> 3x masked LSTM (last hidden) -> segment_sum -> BPR
//   P[v, 0:1024]   = embed[v] @ col_W_ih^T + (col_b_ih + col_b_hh)   (bf16)
//   P[v,1024:2048] = embed[v] @ row_W_ih^T + (row_b_ih + row_b_hh)
//   Recurrence: gates^T = W_hh * h^T via mfma_f32_16x16x32_bf16.
// R2: kill the VGPR spills (R1 had ~92 MB of scratch write traffic/step):
//   - P prefetch moved from 64 VGPRs to wave-private LDS via global_load_lds
//     (per-lane gather source, lane-ordered linear LDS dest), double-buffered
//   - h single-buffered in LDS, 2 lgkmcnt-only barriers/step; frozen lanes
//     simply don't store (no hpk copy regs)
//   - DMA issue pinned after the MFMA k-loop (sched_barrier) so in-order
//     vmcnt never makes W-load waits depend on HBM gathers
// ---------------------------------------------------------------------------

typedef __bf16 bf16x8 __attribute__((ext_vector_type(8)));
typedef float  fvec4  __attribute__((ext_vector_type(4)));

#define NSEN 4096
#define HIDN 256
#define EMBD 300
#define VOC  50000

// workspace layout (bytes)
#define OFF_P     0ULL            // ushort [50000][2048]
#define OFF_WCAT  204800000ULL    // ushort [2048][320]   (ih weights, K padded)
#define OFF_WHHC  206110720ULL    // ushort [262144]      (packed frag order)
#define OFF_WHHR  206635008ULL    // ushort [262144]      (packed frag order)
#define OFF_BIAS  207159296ULL    // float  [2048]
#define OFF_H     207167488ULL    // float  [3][4096][256]
#define OFF_SEG   219750400ULL    // float  [3][4096][256]
#define OFF_LOSS  232333312ULL    // float  [4096]

static __device__ __forceinline__ unsigned short f2bf(float x) {
    unsigned int u = __float_as_uint(x);
    unsigned int r = (u + 0x7fffu + ((u >> 16) & 1u)) >> 16;  // RNE
    return (unsigned short)r;
}
static __device__ __forceinline__ float bf2f(unsigned short b) {
    return __uint_as_float(((unsigned int)b) << 16);
}
static __device__ __forceinline__ float sigm(float x) { return 1.f / (1.f + __expf(-x)); }
static __device__ __forceinline__ float tanh_(float x) {
    float e = __expf(2.f * x);
    return 1.f - 2.f / (e + 1.f);   // stable at +-inf
}
static __device__ __forceinline__ fvec4 unpk(uint2 v) {
    fvec4 o;
    o[0] = __uint_as_float((v.x & 0xffffu) << 16);
    o[1] = __uint_as_float(v.x & 0xffff0000u);
    o[2] = __uint_as_float((v.y & 0xffffu) << 16);
    o[3] = __uint_as_float(v.y & 0xffff0000u);
    return o;
}

// async 16B/lane gather into wave-private LDS (lane-ordered linear dest)
static __device__ __forceinline__ void gld_lds16(const unsigned short* g,
                                                 unsigned short* l)
{
    __builtin_amdgcn_global_load_lds(
        (const __attribute__((address_space(1))) unsigned int*)g,
        (__attribute__((address_space(3))) unsigned int*)l, 16, 0, 0);
}

// Whh packed layout: frag L = (((wv*2+hf)*8+kt)*4+g)*2+uh, elem = L*512 + ln*8 + j
// lane ln holds Whh[row][col], row = g*256+wv*64+(hf*2+uh)*16+(ln&15),
//                              col = kt*32+(ln>>4)*8+j
static __device__ __forceinline__ int whh_src(int o) {
    int L  = o >> 9;
    int r9 = o & 511;
    int ln = r9 >> 3, j = r9 & 7;
    int uh = L & 1, g = (L >> 1) & 3, kt = (L >> 3) & 7;
    int hf = (L >> 6) & 1, wv = (L >> 7) & 3;
    int row = g * 256 + wv * 64 + (hf * 2 + uh) * 16 + (ln & 15);
    int col = kt * 32 + (ln >> 4) * 8 + j;
    return row * 256 + col;
}

// ---------------------------------------------------------------- prep: pack
__global__ void prep_kernel(
    const float* __restrict__ cWih, const float* __restrict__ rWih,
    const float* __restrict__ cWhh, const float* __restrict__ rWhh,
    const float* __restrict__ cbih, const float* __restrict__ cbhh,
    const float* __restrict__ rbih, const float* __restrict__ rbhh,
    unsigned short* __restrict__ Wcat, unsigned short* __restrict__ WhhC,
    unsigned short* __restrict__ WhhR, float* __restrict__ biascat)
{
    int idx = blockIdx.x * 256 + threadIdx.x;
    if (idx < 2048 * 320) {
        int n = idx / 320, k = idx - n * 320;
        float v = 0.f;
        if (k < EMBD) v = (n < 1024) ? cWih[n * EMBD + k] : rWih[(n - 1024) * EMBD + k];
        Wcat[idx] = f2bf(v);
        return;
    }
    idx -= 2048 * 320;
    if (idx < 262144) { WhhC[idx] = f2bf(cWhh[whh_src(idx)]); return; }
    idx -= 262144;
    if (idx < 262144) { WhhR[idx] = f2bf(rWhh[whh_src(idx)]); return; }
    idx -= 262144;
    if (idx < 2048)
        biascat[idx] = (idx < 1024) ? (cbih[idx] + cbhh[idx])
                                    : (rbih[idx - 1024] + rbhh[idx - 1024]);
}

// ------------------------------------------------------- P = embed @ Wcat^T
__global__ __launch_bounds__(256) void gemm_p_kernel(
    const float* __restrict__ A,          // embed [50000][300] fp32
    const unsigned short* __restrict__ Bw,// Wcat  [2048][320] bf16
    const float* __restrict__ bias,       // [2048]
    unsigned short* __restrict__ Pout)    // [50000][2048] bf16
{
    const int nb = blockIdx.x * 128;
    const int mb = blockIdx.y * 128;
    const int tid = threadIdx.x;
    const int wv = tid >> 6, ln = tid & 63, l15 = ln & 15, q = ln >> 4;
    const int wm = wv & 1, wn = wv >> 1;

    __shared__ __align__(16) unsigned short At[128][40]; // [m][k] bf16, pad->40

    fvec4 acc[4][4];
    #pragma unroll
    for (int a = 0; a < 4; ++a)
        #pragma unroll
        for (int b = 0; b < 4; ++b) acc[a][b] = (fvec4)0.f;

    for (int kt = 0; kt < 10; ++kt) {
        const int K0 = kt * 32;
        __syncthreads();
        {
            int tr = tid >> 3;   // 0..31
            int tc = tid & 7;    // float4 column
            #pragma unroll
            for (int p = 0; p < 4; ++p) {
                int rrow = tr + p * 32;
                int gr = mb + rrow;
                float4 v = make_float4(0.f, 0.f, 0.f, 0.f);
                if (gr < VOC && (K0 + tc * 4) < EMBD)
                    v = *(const float4*)(A + (size_t)gr * EMBD + K0 + tc * 4);
                ushort4 b;
                b.x = f2bf(v.x); b.y = f2bf(v.y); b.z = f2bf(v.z); b.w = f2bf(v.w);
                *(ushort4*)&At[rrow][tc * 4] = b;
            }
        }
        __syncthreads();
        bf16x8 bf_[4];
        #pragma unroll
        for (int ntt = 0; ntt < 4; ++ntt) {
            int n = nb + wn * 64 + ntt * 16 + l15;
            bf_[ntt] = *(const bf16x8*)(Bw + (size_t)n * 320 + K0 + q * 8);
        }
        #pragma unroll
        for (int mt = 0; mt < 4; ++mt) {
            bf16x8 af = *(const bf16x8*)&At[wm * 64 + mt * 16 + l15][q * 8];
            #pragma unroll
            for (int ntt = 0; ntt < 4; ++ntt)
                acc[mt][ntt] = __builtin_amdgcn_mfma_f32_16x16x32_bf16(
                    af, bf_[ntt], acc[mt][ntt], 0, 0, 0);
        }
    }
    float bv[4];
    #pragma unroll
    for (int ntt = 0; ntt < 4; ++ntt) bv[ntt] = bias[nb + wn * 64 + ntt * 16 + l15];
    #pragma unroll
    for (int mt = 0; mt < 4; ++mt) {
        #pragma unroll
        for (int r = 0; r < 4; ++r) {
            int m = mb + wm * 64 + mt * 16 + q * 4 + r;
            if (m < VOC) {
                size_t base = (size_t)m * 2048 + nb + wn * 64;
                #pragma unroll
                for (int ntt = 0; ntt < 4; ++ntt)
                    Pout[base + ntt * 16 + l15] = f2bf(acc[mt][ntt][r] + bv[ntt]);
            }
        }
    }
}

// ----------------------------------------------------------------- LSTMs
// grid 384: blocks [0,128) col, [128,256) row, [256,384) row_neg.
// Block: 32 seqs, 4 waves; wave wv owns hidden units [64wv,64wv+64).
// P gathers for step t+1 DMA'd into wave-private LDS during step t;
// h single-buffered, two lgkmcnt-only barriers per step.
__global__ __launch_bounds__(256, 1) void lstm_kernel(
    const int* __restrict__ colTok, const int* __restrict__ rowTok, const int* __restrict__ negTok,
    const int* __restrict__ colLen, const int* __restrict__ rowLen, const int* __restrict__ negLen,
    const unsigned short* __restrict__ P,
    const unsigned short* __restrict__ WhhC, const unsigned short* __restrict__ WhhR,
    float* __restrict__ Hout)
{
    const int part = blockIdx.x >> 7;
    const int sb = blockIdx.x & 127;
    const int s0 = sb * 32;
    const int* tok = part == 0 ? colTok : (part == 1 ? rowTok : negTok);
    const int* len = part == 0 ? colLen : (part == 1 ? rowLen : negLen);
    const unsigned short* Whh = part == 0 ? WhhC : WhhR;
    const int T = part == 0 ? 64 : 16;
    const int pco = part == 0 ? 0 : 1024;
    float* Ho = Hout + (size_t)part * (NSEN * HIDN);

    const int tid = threadIdx.x;
    const int wv = tid >> 6, ln = tid & 63, l15 = ln & 15, q = ln >> 4;

    __shared__ __align__(16) unsigned short hbf[32][264];            // 16.5 KB
    __shared__ __align__(16) unsigned short pstage[2][4][16][64][8]; // 128 KB
    __shared__ int lenS[32];
    __shared__ int mlS;

    for (int i = tid; i < 32 * 264; i += 256) (&hbf[0][0])[i] = 0;
    if (tid < 32) lenS[tid] = len[s0 + tid];
    __syncthreads();
    if (tid == 0) { int m = 0; for (int i = 0; i < 32; ++i) m = max(m, lenS[i]); mlS = m; }
    __syncthreads();
    const int maxlen = mlS;
    const int len0 = lenS[l15], len1 = lenS[16 + l15];

    // per-wave contiguous packed-Whh stream base
    const unsigned short* wbase = Whh + (size_t)wv * 65536 + (size_t)ln * 8;

    float c[4][2][4];
    #pragma unroll
    for (int u = 0; u < 4; ++u)
        #pragma unroll
        for (int n = 0; n < 2; ++n)
            #pragma unroll
            for (int r = 0; r < 4; ++r) c[u][n][r] = 0.f;

    // ---- prologue: DMA-stage P rows for t=0 into pstage[0]
    {
        int tka = tok[(s0 + l15) * T];
        int tkb = tok[(s0 + 16 + l15) * T];
        #pragma unroll
        for (int nt = 0; nt < 2; ++nt) {
            const unsigned short* base =
                P + (size_t)(nt ? tkb : tka) * 2048 + pco + wv * 64 + q * 8;
            #pragma unroll
            for (int g = 0; g < 4; ++g)
                #pragma unroll
                for (int hl = 0; hl < 2; ++hl)
                    gld_lds16(base + g * 256 + hl * 32,
                              &pstage[0][wv][(nt * 4 + g) * 2 + hl][0][0]);
        }
    }
    int tkn0 = tok[(s0 + l15) * T + 1];        // tokens for t=1 (T >= 16)
    int tkn1 = tok[(s0 + 16 + l15) * T + 1];

    for (int t = 0; t < maxlen; ++t) {
        const int b = t & 1, b2 = b ^ 1;
        // wave-private: wait for this wave's stage DMAs (issued last step)
        asm volatile("s_waitcnt vmcnt(0)" ::: "memory");

        ushort4 h0s[2][2];   // hf=0 results, written after barrier #1
        #pragma unroll
        for (int hf = 0; hf < 2; ++hf) {
            // acc init from staged P (wave-private LDS)
            fvec4 acc[4][2][2]; // [g][uh][nt]
            #pragma unroll
            for (int g = 0; g < 4; ++g)
                #pragma unroll
                for (int uh = 0; uh < 2; ++uh) {
                    const int lanep = (uh * 2 + (q >> 1)) * 16 + l15;
                    const int j = (q & 1) * 4;
                    #pragma unroll
                    for (int nt = 0; nt < 2; ++nt)
                        acc[g][uh][nt] = unpk(*(const uint2*)
                            &pstage[b][wv][(nt * 4 + g) * 2 + hf][lanep][j]);
                }

            // gates += Whh_half * h^T  (contiguous packed frag stream, L2)
            #pragma unroll
            for (int kt = 0; kt < 8; ++kt) {
                bf16x8 b0 = *(const bf16x8*)&hbf[l15][kt * 32 + q * 8];
                bf16x8 b1 = *(const bf16x8*)&hbf[16 + l15][kt * 32 + q * 8];
                const unsigned short* wp = wbase + (size_t)(hf * 8 + kt) * 4096;
                #pragma unroll
                for (int g = 0; g < 4; ++g) {
                    #pragma unroll
                    for (int uh = 0; uh < 2; ++uh) {
                        bf16x8 a = *(const bf16x8*)(wp + (size_t)(g * 2 + uh) * 512);
                        acc[g][uh][0] = __builtin_amdgcn_mfma_f32_16x16x32_bf16(a, b0, acc[g][uh][0], 0, 0, 0);
                        acc[g][uh][1] = __builtin_amdgcn_mfma_f32_16x16x32_bf16(a, b1, acc[g][uh][1], 0, 0, 0);
                    }
                }
            }

            if (hf == 1) {
                // all h reads + all W waits done; now issue next step's DMAs.
                // sched_barrier pins them after the k-loop so in-order vmcnt
                // never couples W-load waits to these HBM gathers.
                __builtin_amdgcn_sched_barrier(0);
                #pragma unroll
                for (int nt = 0; nt < 2; ++nt) {
                    const unsigned short* base =
                        P + (size_t)(nt ? tkn1 : tkn0) * 2048 + pco + wv * 64 + q * 8;
                    #pragma unroll
                    for (int g = 0; g < 4; ++g)
                        #pragma unroll
                        for (int hl = 0; hl < 2; ++hl)
                            gld_lds16(base + g * 256 + hl * 32,
                                      &pstage[b2][wv][(nt * 4 + g) * 2 + hl][0][0]);
                }
                int t2 = (t + 2 < T) ? (t + 2) : (T - 1);
                tkn0 = tok[(s0 + l15) * T + t2];
                tkn1 = tok[(s0 + 16 + l15) * T + t2];
                // barrier #1: all waves' h reads complete before any h write
                asm volatile("s_waitcnt lgkmcnt(0)\n\ts_barrier" ::: "memory");
            }

            // activation; hf=0 defers its h store until after barrier #1
            #pragma unroll
            for (int uh = 0; uh < 2; ++uh) {
                const int u = hf * 2 + uh;
                #pragma unroll
                for (int nt = 0; nt < 2; ++nt) {
                    bool act = t < (nt ? len1 : len0);
                    if (act) {
                        float hr[4];
                        #pragma unroll
                        for (int r = 0; r < 4; ++r) {
                            float iv = acc[0][uh][nt][r];
                            float fv = acc[1][uh][nt][r];
                            float gv = acc[2][uh][nt][r];
                            float ov = acc[3][uh][nt][r];
                            float cn = sigm(fv) * c[u][nt][r] + sigm(iv) * tanh_(gv);
                            c[u][nt][r] = cn;
                            hr[r] = sigm(ov) * tanh_(cn);
                        }
                        ushort4 hv = make_ushort4(f2bf(hr[0]), f2bf(hr[1]),
                                                  f2bf(hr[2]), f2bf(hr[3]));
                        if (hf == 0) {
                            h0s[uh][nt] = hv;
                        } else {
                            *(ushort4*)&hbf[nt * 16 + l15][wv * 64 + u * 16 + q * 4] = hv;
                            *(ushort4*)&hbf[nt * 16 + l15][wv * 64 + uh * 16 + q * 4] = h0s[uh][nt];
                        }
                    }
                    // frozen lanes: single-buffered h keeps the old value
                }
            }
        }
        // barrier #2: h writes visible before next step's reads
        asm volatile("s_waitcnt lgkmcnt(0)\n\ts_barrier" ::: "memory");
    }

    for (int i = tid; i < 32 * HIDN; i += 256) {
        int sq = i >> 8, hd = i & 255;
        Ho[(size_t)(s0 + sq) * HIDN + hd] = bf2f(hbf[sq][hd]);
    }
}

// ------------------------------------------------------------ segment sum
__global__ void scatter_kernel(const float* __restrict__ Hout,
                               const int* __restrict__ crefs, const int* __restrict__ rrefs,
                               const int* __restrict__ nrefs, float* __restrict__ seg)
{
    int idx = blockIdx.x * 256 + threadIdx.x;       // < 3 * 2^20
    int which = idx >> 20;
    int rem = idx & 1048575;
    int s = rem >> 8, hd = rem & 255;
    const int* refs = which == 0 ? crefs : (which == 1 ? rrefs : nrefs);
    int rf = refs[s];
    atomicAdd(&seg[(size_t)which * 1048576 + (size_t)rf * 256 + hd], Hout[idx]);
}

// ------------------------------------------------------------------ loss
__global__ void loss_kernel(const float* __restrict__ seg, float* __restrict__ part)
{
    int d = blockIdx.x, tid = threadIdx.x;
    const float* sc = seg + (size_t)d * 256;
    const float* sr = seg + 1048576 + (size_t)d * 256;
    const float* sn = seg + 2097152 + (size_t)d * 256;
    float a = sc[tid];
    float p = a * sr[tid];
    float n = a * sn[tid];
    for (int off = 32; off; off >>= 1) { p += __shfl_down(p, off); n += __shfl_down(n, off); }
    __shared__ float rp[4], rn[4];
    if ((tid & 63) == 0) { rp[tid >> 6] = p; rn[tid >> 6] = n; }
    __syncthreads();
    if (tid == 0) {
        float Ps = rp[0] + rp[1] + rp[2] + rp[3];
        float Ns = rn[0] + rn[1] + rn[2] + rn[3];
        float x = Ps - Ns;
        part[d] = fmaxf(-x, 0.f) + log1pf(expf(-fabsf(x)));  // softplus(-x)
    }
}

__global__ void reduce_kernel(const float* __restrict__ part, float* __restrict__ out)
{
    int tid = threadIdx.x;
    float s = 0.f;
    for (int i = tid; i < 4096; i += 256) s += part[i];
    for (int off = 32; off; off >>= 1) s += __shfl_down(s, off);
    __shared__ float r[4];
    if ((tid & 63) == 0) r[tid >> 6] = s;
    __syncthreads();
    if (tid == 0) out[0] = r[0] + r[1] + r[2] + r[3];
}

// ---------------------------------------------------------------------------
extern "C" void kernel_launch(void* const* d_in, const int* in_sizes, int n_in,
                              void* d_out, int out_size, void* d_ws, size_t ws_size,
                              hipStream_t stream)
{
    const int*   col      = (const int*)d_in[0];
    const int*   row      = (const int*)d_in[1];
    const int*   rneg     = (const int*)d_in[2];
    const int*   col_lens = (const int*)d_in[3];
    const int*   row_lens = (const int*)d_in[4];
    const int*   rng_lens = (const int*)d_in[5];
    const int*   col_refs = (const int*)d_in[6];
    const int*   row_refs = (const int*)d_in[7];
    const int*   rng_refs = (const int*)d_in[8];
    const float* embed    = (const float*)d_in[9];
    const float* cWih     = (const float*)d_in[10];
    const float* cWhh     = (const float*)d_in[11];
    const float* cbih     = (const float*)d_in[12];
    const float* cbhh     = (const float*)d_in[13];
    const float* rWih     = (const float*)d_in[14];
    const float* rWhh     = (const float*)d_in[15];
    const float* rbih     = (const float*)d_in[16];
    const float* rbhh     = (const float*)d_in[17];

    char* ws = (char*)d_ws;
    unsigned short* P    = (unsigned short*)(ws + OFF_P);
    unsigned short* Wcat = (unsigned short*)(ws + OFF_WCAT);
    unsigned short* WhhC = (unsigned short*)(ws + OFF_WHHC);
    unsigned short* WhhR = (unsigned short*)(ws + OFF_WHHR);
    float* biascat = (float*)(ws + OFF_BIAS);
    float* Hbuf    = (float*)(ws + OFF_H);
    float* seg     = (float*)(ws + OFF_SEG);
    float* lpart   = (float*)(ws + OFF_LOSS);

    hipMemsetAsync(seg, 0, 3 * 4096 * 256 * sizeof(float), stream);

    prep_kernel<<<4616, 256, 0, stream>>>(cWih, rWih, cWhh, rWhh,
                                          cbih, cbhh, rbih, rbhh,
                                          Wcat, WhhC, WhhR, biascat);
    gemm_p_kernel<<<dim3(16, 391), 256, 0, stream>>>(embed, Wcat, biascat, P);
    lstm_kernel<<<384, 256, 0, stream>>>(col, row, rneg,
                                         col_lens, row_lens, rng_lens,
                                         P, WhhC, WhhR, Hbuf);
    scatter_kernel<<<12288, 256, 0, stream>>>(Hbuf, col_refs, row_refs, rng_refs, seg);
    loss_kernel<<<4096, 256, 0, stream>>>(seg, lpart);
    reduce_kernel<<<1, 256, 0, stream>>>(lpart, (float*)d_out);
}

// Round 3
// 1512.618 us; speedup vs baseline: 1.2234x; 1.2234x over previous
//
#include <hip/hip_runtime.h>

// ---------------------------------------------------------------------------
// NaryCompUSchema: embed -> 3x masked LSTM (last hidden) -> segment_sum -> BPR
//   P[v, 0:1024]   = embed[v] @ col_W_ih^T + (col_b_ih + col_b_hh)   (bf16)
//   P[v,1024:2048] = embed[v] @ row_W_ih^T + (row_b_ih + row_b_hh)
//   Recurrence: gates^T = W_hh * h^T via mfma_f32_16x16x32_bf16.
// R3: attack per-step latency tau (~23us across R0/R1/R2, invariant):
//   - kt loop partially unrolled (#pragma unroll 2): step body ~25KB -> ~4KB
//     (I-fetch-bound hypothesis; straight-line body refetched every step)
//   - LDS 148KB -> 80KB (2 blocks/CU): single-buffered wave-private pstage
//     (re-issue guarded by lgkmcnt(0)), hbf de-padded [32][256] with XOR
//     swizzle (row&7)<<4 on byte addr, lens via shfl (no LDS)
// ---------------------------------------------------------------------------

typedef __bf16 bf16x8 __attribute__((ext_vector_type(8)));
typedef float  fvec4  __attribute__((ext_vector_type(4)));

#define NSEN 4096
#define HIDN 256
#define EMBD 300
#define VOC  50000

// workspace layout (bytes)
#define OFF_P     0ULL            // ushort [50000][2048]
#define OFF_WCAT  204800000ULL    // ushort [2048][320]   (ih weights, K padded)
#define OFF_WHHC  206110720ULL    // ushort [262144]      (packed frag order)
#define OFF_WHHR  206635008ULL    // ushort [262144]      (packed frag order)
#define OFF_BIAS  207159296ULL    // float  [2048]
#define OFF_H     207167488ULL    // float  [3][4096][256]
#define OFF_SEG   219750400ULL    // float  [3][4096][256]
#define OFF_LOSS  232333312ULL    // float  [4096]

static __device__ __forceinline__ unsigned short f2bf(float x) {
    unsigned int u = __float_as_uint(x);
    unsigned int r = (u + 0x7fffu + ((u >> 16) & 1u)) >> 16;  // RNE
    return (unsigned short)r;
}
static __device__ __forceinline__ float bf2f(unsigned short b) {
    return __uint_as_float(((unsigned int)b) << 16);
}
static __device__ __forceinline__ float sigm(float x) { return 1.f / (1.f + __expf(-x)); }
static __device__ __forceinline__ float tanh_(float x) {
    float e = __expf(2.f * x);
    return 1.f - 2.f / (e + 1.f);   // stable at +-inf
}
static __device__ __forceinline__ fvec4 unpk(uint2 v) {
    fvec4 o;
    o[0] = __uint_as_float((v.x & 0xffffu) << 16);
    o[1] = __uint_as_float(v.x & 0xffff0000u);
    o[2] = __uint_as_float((v.y & 0xffffu) << 16);
    o[3] = __uint_as_float(v.y & 0xffff0000u);
    return o;
}

// async 16B/lane gather into wave-private LDS (lane-ordered linear dest)
static __device__ __forceinline__ void gld_lds16(const unsigned short* g,
                                                 unsigned short* l)
{
    __builtin_amdgcn_global_load_lds(
        (const __attribute__((address_space(1))) unsigned int*)g,
        (__attribute__((address_space(3))) unsigned int*)l, 16, 0, 0);
}

// Whh packed layout: frag L = (((wv*2+hf)*8+kt)*4+g)*2+uh, elem = L*512 + ln*8 + j
// lane ln holds Whh[row][col], row = g*256+wv*64+(hf*2+uh)*16+(ln&15),
//                              col = kt*32+(ln>>4)*8+j
static __device__ __forceinline__ int whh_src(int o) {
    int L  = o >> 9;
    int r9 = o & 511;
    int ln = r9 >> 3, j = r9 & 7;
    int uh = L & 1, g = (L >> 1) & 3, kt = (L >> 3) & 7;
    int hf = (L >> 6) & 1, wv = (L >> 7) & 3;
    int row = g * 256 + wv * 64 + (hf * 2 + uh) * 16 + (ln & 15);
    int col = kt * 32 + (ln >> 4) * 8 + j;
    return row * 256 + col;
}

// ---------------------------------------------------------------- prep: pack
__global__ void prep_kernel(
    const float* __restrict__ cWih, const float* __restrict__ rWih,
    const float* __restrict__ cWhh, const float* __restrict__ rWhh,
    const float* __restrict__ cbih, const float* __restrict__ cbhh,
    const float* __restrict__ rbih, const float* __restrict__ rbhh,
    unsigned short* __restrict__ Wcat, unsigned short* __restrict__ WhhC,
    unsigned short* __restrict__ WhhR, float* __restrict__ biascat)
{
    int idx = blockIdx.x * 256 + threadIdx.x;
    if (idx < 2048 * 320) {
        int n = idx / 320, k = idx - n * 320;
        float v = 0.f;
        if (k < EMBD) v = (n < 1024) ? cWih[n * EMBD + k] : rWih[(n - 1024) * EMBD + k];
        Wcat[idx] = f2bf(v);
        return;
    }
    idx -= 2048 * 320;
    if (idx < 262144) { WhhC[idx] = f2bf(cWhh[whh_src(idx)]); return; }
    idx -= 262144;
    if (idx < 262144) { WhhR[idx] = f2bf(rWhh[whh_src(idx)]); return; }
    idx -= 262144;
    if (idx < 2048)
        biascat[idx] = (idx < 1024) ? (cbih[idx] + cbhh[idx])
                                    : (rbih[idx - 1024] + rbhh[idx - 1024]);
}

// ------------------------------------------------------- P = embed @ Wcat^T
__global__ __launch_bounds__(256) void gemm_p_kernel(
    const float* __restrict__ A,          // embed [50000][300] fp32
    const unsigned short* __restrict__ Bw,// Wcat  [2048][320] bf16
    const float* __restrict__ bias,       // [2048]
    unsigned short* __restrict__ Pout)    // [50000][2048] bf16
{
    const int nb = blockIdx.x * 128;
    const int mb = blockIdx.y * 128;
    const int tid = threadIdx.x;
    const int wv = tid >> 6, ln = tid & 63, l15 = ln & 15, q = ln >> 4;
    const int wm = wv & 1, wn = wv >> 1;

    __shared__ __align__(16) unsigned short At[128][40]; // [m][k] bf16, pad->40

    fvec4 acc[4][4];
    #pragma unroll
    for (int a = 0; a < 4; ++a)
        #pragma unroll
        for (int b = 0; b < 4; ++b) acc[a][b] = (fvec4)0.f;

    for (int kt = 0; kt < 10; ++kt) {
        const int K0 = kt * 32;
        __syncthreads();
        {
            int tr = tid >> 3;   // 0..31
            int tc = tid & 7;    // float4 column
            #pragma unroll
            for (int p = 0; p < 4; ++p) {
                int rrow = tr + p * 32;
                int gr = mb + rrow;
                float4 v = make_float4(0.f, 0.f, 0.f, 0.f);
                if (gr < VOC && (K0 + tc * 4) < EMBD)
                    v = *(const float4*)(A + (size_t)gr * EMBD + K0 + tc * 4);
                ushort4 b;
                b.x = f2bf(v.x); b.y = f2bf(v.y); b.z = f2bf(v.z); b.w = f2bf(v.w);
                *(ushort4*)&At[rrow][tc * 4] = b;
            }
        }
        __syncthreads();
        bf16x8 bf_[4];
        #pragma unroll
        for (int ntt = 0; ntt < 4; ++ntt) {
            int n = nb + wn * 64 + ntt * 16 + l15;
            bf_[ntt] = *(const bf16x8*)(Bw + (size_t)n * 320 + K0 + q * 8);
        }
        #pragma unroll
        for (int mt = 0; mt < 4; ++mt) {
            bf16x8 af = *(const bf16x8*)&At[wm * 64 + mt * 16 + l15][q * 8];
            #pragma unroll
            for (int ntt = 0; ntt < 4; ++ntt)
                acc[mt][ntt] = __builtin_amdgcn_mfma_f32_16x16x32_bf16(
                    af, bf_[ntt], acc[mt][ntt], 0, 0, 0);
        }
    }
    float bv[4];
    #pragma unroll
    for (int ntt = 0; ntt < 4; ++ntt) bv[ntt] = bias[nb + wn * 64 + ntt * 16 + l15];
    #pragma unroll
    for (int mt = 0; mt < 4; ++mt) {
        #pragma unroll
        for (int r = 0; r < 4; ++r) {
            int m = mb + wm * 64 + mt * 16 + q * 4 + r;
            if (m < VOC) {
                size_t base = (size_t)m * 2048 + nb + wn * 64;
                #pragma unroll
                for (int ntt = 0; ntt < 4; ++ntt)
                    Pout[base + ntt * 16 + l15] = f2bf(acc[mt][ntt][r] + bv[ntt]);
            }
        }
    }
}

// ----------------------------------------------------------------- LSTMs
// grid 384: blocks [0,128) col, [128,256) row, [256,384) row_neg.
// Block: 32 seqs, 4 waves; wave wv owns hidden units [64wv,64wv+64).
// LDS 80KB -> 2 blocks/CU. pstage single-buffered (wave-private, lgkm guard
// before re-issue). hbf XOR-swizzled, no pad. kt loop unroll-2 (small body).
__global__ __launch_bounds__(256, 1) void lstm_kernel(
    const int* __restrict__ colTok, const int* __restrict__ rowTok, const int* __restrict__ negTok,
    const int* __restrict__ colLen, const int* __restrict__ rowLen, const int* __restrict__ negLen,
    const unsigned short* __restrict__ P,
    const unsigned short* __restrict__ WhhC, const unsigned short* __restrict__ WhhR,
    float* __restrict__ Hout)
{
    const int part = blockIdx.x >> 7;
    const int sb = blockIdx.x & 127;
    const int s0 = sb * 32;
    const int* tok = part == 0 ? colTok : (part == 1 ? rowTok : negTok);
    const int* len = part == 0 ? colLen : (part == 1 ? rowLen : negLen);
    const unsigned short* Whh = part == 0 ? WhhC : WhhR;
    const int T = part == 0 ? 64 : 16;
    const int pco = part == 0 ? 0 : 1024;
    float* Ho = Hout + (size_t)part * (NSEN * HIDN);

    const int tid = threadIdx.x;
    const int wv = tid >> 6, ln = tid & 63, l15 = ln & 15, q = ln >> 4;

    __shared__ __align__(16) unsigned short hbf[32][256];      // 16 KB, swizzled
    __shared__ __align__(16) unsigned short pstage[4][16][64][8]; // 64 KB
    char* hB = (char*)&hbf[0][0];
    const int swz = (l15 & 7) << 4;   // XOR swizzle for this lane's h rows

    for (int i = tid; i < 32 * 256; i += 256) (&hbf[0][0])[i] = 0;

    // lens without LDS: per-lane loads + shfl-xor max over the 32 seqs
    const int len0 = len[s0 + l15];
    const int len1 = len[s0 + 16 + l15];
    int ml = max(len0, len1);
    #pragma unroll
    for (int off = 1; off < 16; off <<= 1) ml = max(ml, __shfl_xor(ml, off));
    const int maxlen = ml;

    // per-wave contiguous packed-Whh stream base
    const unsigned short* wbase = Whh + (size_t)wv * 65536 + (size_t)ln * 8;

    float c[4][2][4];
    #pragma unroll
    for (int u = 0; u < 4; ++u)
        #pragma unroll
        for (int n = 0; n < 2; ++n)
            #pragma unroll
            for (int r = 0; r < 4; ++r) c[u][n][r] = 0.f;

    __syncthreads();   // hbf zero-init visible

    // ---- prologue: DMA-stage P rows for t=0
    {
        int tka = tok[(s0 + l15) * T];
        int tkb = tok[(s0 + 16 + l15) * T];
        #pragma unroll
        for (int nt = 0; nt < 2; ++nt) {
            const unsigned short* base =
                P + (size_t)(nt ? tkb : tka) * 2048 + pco + wv * 64 + q * 8;
            #pragma unroll
            for (int g = 0; g < 4; ++g)
                #pragma unroll
                for (int hl = 0; hl < 2; ++hl)
                    gld_lds16(base + g * 256 + hl * 32,
                              &pstage[wv][(nt * 4 + g) * 2 + hl][0][0]);
        }
    }
    int tkn0 = tok[(s0 + l15) * T + 1];        // tokens for t=1 (T >= 16)
    int tkn1 = tok[(s0 + 16 + l15) * T + 1];

    for (int t = 0; t < maxlen; ++t) {
        // wave-private: wait for this wave's stage DMAs (issued last step)
        asm volatile("s_waitcnt vmcnt(0)" ::: "memory");

        ushort4 h0s[2][2];   // hf=0 results, written after barrier #1
        #pragma unroll
        for (int hf = 0; hf < 2; ++hf) {
            // acc init from staged P (wave-private LDS)
            fvec4 acc[4][2][2]; // [g][uh][nt]
            #pragma unroll
            for (int g = 0; g < 4; ++g)
                #pragma unroll
                for (int uh = 0; uh < 2; ++uh) {
                    const int lanep = (uh * 2 + (q >> 1)) * 16 + l15;
                    const int j = (q & 1) * 4;
                    #pragma unroll
                    for (int nt = 0; nt < 2; ++nt)
                        acc[g][uh][nt] = unpk(*(const uint2*)
                            &pstage[wv][(nt * 4 + g) * 2 + hf][lanep][j]);
                }

            // gates += Whh_half * h^T  (contiguous packed frag stream, L2)
            // unroll 2: keep code footprint small (I-fetch), 2-deep load pipe
            #pragma unroll 2
            for (int kt = 0; kt < 8; ++kt) {
                bf16x8 b0 = *(const bf16x8*)(hB + l15 * 512 + ((kt * 64 + q * 16) ^ swz));
                bf16x8 b1 = *(const bf16x8*)(hB + (16 + l15) * 512 + ((kt * 64 + q * 16) ^ swz));
                const unsigned short* wp = wbase + (size_t)(hf * 8 + kt) * 4096;
                #pragma unroll
                for (int g = 0; g < 4; ++g) {
                    #pragma unroll
                    for (int uh = 0; uh < 2; ++uh) {
                        bf16x8 a = *(const bf16x8*)(wp + (size_t)(g * 2 + uh) * 512);
                        acc[g][uh][0] = __builtin_amdgcn_mfma_f32_16x16x32_bf16(a, b0, acc[g][uh][0], 0, 0, 0);
                        acc[g][uh][1] = __builtin_amdgcn_mfma_f32_16x16x32_bf16(a, b1, acc[g][uh][1], 0, 0, 0);
                    }
                }
            }

            if (hf == 1) {
                // guard: all this wave's pstage/h ds_reads complete before the
                // DMAs that overwrite the (wave-private) pstage region
                __builtin_amdgcn_sched_barrier(0);
                asm volatile("s_waitcnt lgkmcnt(0)" ::: "memory");
                #pragma unroll
                for (int nt = 0; nt < 2; ++nt) {
                    const unsigned short* base =
                        P + (size_t)(nt ? tkn1 : tkn0) * 2048 + pco + wv * 64 + q * 8;
                    #pragma unroll
                    for (int g = 0; g < 4; ++g)
                        #pragma unroll
                        for (int hl = 0; hl < 2; ++hl)
                            gld_lds16(base + g * 256 + hl * 32,
                                      &pstage[wv][(nt * 4 + g) * 2 + hl][0][0]);
                }
                int t2 = (t + 2 < T) ? (t + 2) : (T - 1);
                tkn0 = tok[(s0 + l15) * T + t2];
                tkn1 = tok[(s0 + 16 + l15) * T + t2];
                // barrier #1: all waves' h reads complete before any h write
                asm volatile("s_waitcnt lgkmcnt(0)\n\ts_barrier" ::: "memory");
            }

            // activation; hf=0 defers its h store until after barrier #1
            #pragma unroll
            for (int uh = 0; uh < 2; ++uh) {
                const int u = hf * 2 + uh;
                #pragma unroll
                for (int nt = 0; nt < 2; ++nt) {
                    bool act = t < (nt ? len1 : len0);
                    int srow = nt * 16 + l15;
                    if (act) {
                        float hr[4];
                        #pragma unroll
                        for (int r = 0; r < 4; ++r) {
                            float iv = acc[0][uh][nt][r];
                            float fv = acc[1][uh][nt][r];
                            float gv = acc[2][uh][nt][r];
                            float ov = acc[3][uh][nt][r];
                            float cn = sigm(fv) * c[u][nt][r] + sigm(iv) * tanh_(gv);
                            c[u][nt][r] = cn;
                            hr[r] = sigm(ov) * tanh_(cn);
                        }
                        ushort4 hv = make_ushort4(f2bf(hr[0]), f2bf(hr[1]),
                                                  f2bf(hr[2]), f2bf(hr[3]));
                        if (hf == 0) {
                            h0s[uh][nt] = hv;
                        } else {
                            *(ushort4*)(hB + srow * 512 + ((wv * 128 + u * 32 + q * 8) ^ swz)) = hv;
                            *(ushort4*)(hB + srow * 512 + ((wv * 128 + uh * 32 + q * 8) ^ swz)) = h0s[uh][nt];
                        }
                    }
                    // frozen lanes: single-buffered h keeps the old value
                }
            }
        }
        // barrier #2: h writes visible before next step's reads
        asm volatile("s_waitcnt lgkmcnt(0)\n\ts_barrier" ::: "memory");
    }

    for (int i = tid; i < 32 * HIDN; i += 256) {
        int sq = i >> 8, hd = i & 255;
        unsigned short hv = *(const unsigned short*)
            (hB + sq * 512 + ((hd * 2) ^ ((sq & 7) << 4)));
        Ho[(size_t)(s0 + sq) * HIDN + hd] = bf2f(hv);
    }
}

// ------------------------------------------------------------ segment sum
__global__ void scatter_kernel(const float* __restrict__ Hout,
                               const int* __restrict__ crefs, const int* __restrict__ rrefs,
                               const int* __restrict__ nrefs, float* __restrict__ seg)
{
    int idx = blockIdx.x * 256 + threadIdx.x;       // < 3 * 2^20
    int which = idx >> 20;
    int rem = idx & 1048575;
    int s = rem >> 8, hd = rem & 255;
    const int* refs = which == 0 ? crefs : (which == 1 ? rrefs : nrefs);
    int rf = refs[s];
    atomicAdd(&seg[(size_t)which * 1048576 + (size_t)rf * 256 + hd], Hout[idx]);
}

// ------------------------------------------------------------------ loss
__global__ void loss_kernel(const float* __restrict__ seg, float* __restrict__ part)
{
    int d = blockIdx.x, tid = threadIdx.x;
    const float* sc = seg + (size_t)d * 256;
    const float* sr = seg + 1048576 + (size_t)d * 256;
    const float* sn = seg + 2097152 + (size_t)d * 256;
    float a = sc[tid];
    float p = a * sr[tid];
    float n = a * sn[tid];
    for (int off = 32; off; off >>= 1) { p += __shfl_down(p, off); n += __shfl_down(n, off); }
    __shared__ float rp[4], rn[4];
    if ((tid & 63) == 0) { rp[tid >> 6] = p; rn[tid >> 6] = n; }
    __syncthreads();
    if (tid == 0) {
        float Ps = rp[0] + rp[1] + rp[2] + rp[3];
        float Ns = rn[0] + rn[1] + rn[2] + rn[3];
        float x = Ps - Ns;
        part[d] = fmaxf(-x, 0.f) + log1pf(expf(-fabsf(x)));  // softplus(-x)
    }
}

__global__ void reduce_kernel(const float* __restrict__ part, float* __restrict__ out)
{
    int tid = threadIdx.x;
    float s = 0.f;
    for (int i = tid; i < 4096; i += 256) s += part[i];
    for (int off = 32; off; off >>= 1) s += __shfl_down(s, off);
    __shared__ float r[4];
    if ((tid & 63) == 0) r[tid >> 6] = s;
    __syncthreads();
    if (tid == 0) out[0] = r[0] + r[1] + r[2] + r[3];
}

// ---------------------------------------------------------------------------
extern "C" void kernel_launch(void* const* d_in, const int* in_sizes, int n_in,
                              void* d_out, int out_size, void* d_ws, size_t ws_size,
                              hipStream_t stream)
{
    const int*   col      = (const int*)d_in[0];
    const int*   row      = (const int*)d_in[1];
    const int*   rneg     = (const int*)d_in[2];
    const int*   col_lens = (const int*)d_in[3];
    const int*   row_lens = (const int*)d_in[4];
    const int*   rng_lens = (const int*)d_in[5];
    const int*   col_refs = (const int*)d_in[6];
    const int*   row_refs = (const int*)d_in[7];
    const int*   rng_refs = (const int*)d_in[8];
    const float* embed    = (const float*)d_in[9];
    const float* cWih     = (const float*)d_in[10];
    const float* cWhh     = (const float*)d_in[11];
    const float* cbih     = (const float*)d_in[12];
    const float* cbhh     = (const float*)d_in[13];
    const float* rWih     = (const float*)d_in[14];
    const float* rWhh     = (const float*)d_in[15];
    const float* rbih     = (const float*)d_in[16];
    const float* rbhh     = (const float*)d_in[17];

    char* ws = (char*)d_ws;
    unsigned short* P    = (unsigned short*)(ws + OFF_P);
    unsigned short* Wcat = (unsigned short*)(ws + OFF_WCAT);
    unsigned short* WhhC = (unsigned short*)(ws + OFF_WHHC);
    unsigned short* WhhR = (unsigned short*)(ws + OFF_WHHR);
    float* biascat = (float*)(ws + OFF_BIAS);
    float* Hbuf    = (float*)(ws + OFF_H);
    float* seg     = (float*)(ws + OFF_SEG);
    float* lpart   = (float*)(ws + OFF_LOSS);

    hipMemsetAsync(seg, 0, 3 * 4096 * 256 * sizeof(float), stream);

    prep_kernel<<<4616, 256, 0, stream>>>(cWih, rWih, cWhh, rWhh,
                                          cbih, cbhh, rbih, rbhh,
                                          Wcat, WhhC, WhhR, biascat);
    gemm_p_kernel<<<dim3(16, 391), 256, 0, stream>>>(embed, Wcat, biascat, P);
    lstm_kernel<<<384, 256, 0, stream>>>(col, row, rneg,
                                         col_lens, row_lens, rng_lens,
                                         P, WhhC, WhhR, Hbuf);
    scatter_kernel<<<12288, 256, 0, stream>>>(Hbuf, col_refs, row_refs, rng_refs, seg);
    loss_kernel<<<4096, 256, 0, stream>>>(seg, lpart);
    reduce_kernel<<<1, 256, 0, stream>>>(lpart, (float*)d_out);
}

// Round 5
// 1059.431 us; speedup vs baseline: 1.7467x; 1.4278x over previous
//
#include <hip/hip_runtime.h>

// ---------------------------------------------------------------------------
// NaryCompUSchema: embed -> 3x masked LSTM (last hidden) -> segment_sum -> BPR
//   P[v, 0:1024]   = embed[v] @ col_W_ih^T + (col_b_ih + col_b_hh)   (bf16)
//   P[v,1024:2048] = embed[v] @ row_W_ih^T + (row_b_ih + row_b_hh)
//   Recurrence: gates^T = W_hh * h^T via mfma_f32_16x16x32_bf16.
// R5 == R4 resubmit (R4 bench died to container infra; kernel audited clean):
// the wall is the TAIL (one block alive per CU = 1 wave/SIMD, every VMEM op
// pays full L2 latency serially; tau pinned ~17-24us across R0-R3).
// Restructure: 16 waves x 16 hidden units (1024 thr/block):
//   - per-wave VMEM/step 145 -> ~38; 4 waves/SIMD even when block runs alone
//   - W_hh repacked as per-wave contiguous 32KB streams
//   - P prefetch: 4 global_load_lds (1KB) per wave into gate-major pstage
//   - h double-buffered (2x16KB) -> ONE lgkmcnt-only barrier per step
//   - VGPR <= 128 enforced (launch_bounds(1024,4)) so all 16 waves resident
// ---------------------------------------------------------------------------

typedef __bf16 bf16x8 __attribute__((ext_vector_type(8)));
typedef float  fvec4  __attribute__((ext_vector_type(4)));

#define NSEN 4096
#define HIDN 256
#define EMBD 300
#define VOC  50000

// workspace layout (bytes)
#define OFF_P     0ULL            // ushort [50000][2048]
#define OFF_WCAT  204800000ULL    // ushort [2048][320]   (ih weights, K padded)
#define OFF_WHHC  206110720ULL    // ushort [262144]      (packed frag order)
#define OFF_WHHR  206635008ULL    // ushort [262144]      (packed frag order)
#define OFF_BIAS  207159296ULL    // float  [2048]
#define OFF_H     207167488ULL    // float  [3][4096][256]
#define OFF_SEG   219750400ULL    // float  [3][4096][256]
#define OFF_LOSS  232333312ULL    // float  [4096]

static __device__ __forceinline__ unsigned short f2bf(float x) {
    unsigned int u = __float_as_uint(x);
    unsigned int r = (u + 0x7fffu + ((u >> 16) & 1u)) >> 16;  // RNE
    return (unsigned short)r;
}
static __device__ __forceinline__ float bf2f(unsigned short b) {
    return __uint_as_float(((unsigned int)b) << 16);
}
static __device__ __forceinline__ float sigm(float x) { return 1.f / (1.f + __expf(-x)); }
static __device__ __forceinline__ float tanh_(float x) {
    float e = __expf(2.f * x);
    return 1.f - 2.f / (e + 1.f);   // stable at +-inf
}
static __device__ __forceinline__ fvec4 unpk(uint2 v) {
    fvec4 o;
    o[0] = __uint_as_float((v.x & 0xffffu) << 16);
    o[1] = __uint_as_float(v.x & 0xffff0000u);
    o[2] = __uint_as_float((v.y & 0xffffu) << 16);
    o[3] = __uint_as_float(v.y & 0xffff0000u);
    return o;
}

// async 16B/lane gather into wave-private LDS (lane-ordered linear dest)
static __device__ __forceinline__ void gld_lds16(const unsigned short* g,
                                                 unsigned short* l)
{
    __builtin_amdgcn_global_load_lds(
        (const __attribute__((address_space(1))) unsigned int*)g,
        (__attribute__((address_space(3))) unsigned int*)l, 16, 0, 0);
}

// Whh packed layout (16-wave): frag L = (wv<<5)|(kt<<2)|g, elem = L*512+ln*8+j
// lane ln holds Whh[row][col], row = g*256 + wv*16 + (ln&15),
//                              col = kt*32 + (ln>>4)*8 + j
static __device__ __forceinline__ int whh_src(int o) {
    int L  = o >> 9;
    int r9 = o & 511;
    int ln = r9 >> 3, j = r9 & 7;
    int g  = L & 3, kt = (L >> 2) & 7, wv = (L >> 5) & 15;
    int row = g * 256 + wv * 16 + (ln & 15);
    int col = kt * 32 + (ln >> 4) * 8 + j;
    return row * 256 + col;
}

// ---------------------------------------------------------------- prep: pack
__global__ void prep_kernel(
    const float* __restrict__ cWih, const float* __restrict__ rWih,
    const float* __restrict__ cWhh, const float* __restrict__ rWhh,
    const float* __restrict__ cbih, const float* __restrict__ cbhh,
    const float* __restrict__ rbih, const float* __restrict__ rbhh,
    unsigned short* __restrict__ Wcat, unsigned short* __restrict__ WhhC,
    unsigned short* __restrict__ WhhR, float* __restrict__ biascat)
{
    int idx = blockIdx.x * 256 + threadIdx.x;
    if (idx < 2048 * 320) {
        int n = idx / 320, k = idx - n * 320;
        float v = 0.f;
        if (k < EMBD) v = (n < 1024) ? cWih[n * EMBD + k] : rWih[(n - 1024) * EMBD + k];
        Wcat[idx] = f2bf(v);
        return;
    }
    idx -= 2048 * 320;
    if (idx < 262144) { WhhC[idx] = f2bf(cWhh[whh_src(idx)]); return; }
    idx -= 262144;
    if (idx < 262144) { WhhR[idx] = f2bf(rWhh[whh_src(idx)]); return; }
    idx -= 262144;
    if (idx < 2048)
        biascat[idx] = (idx < 1024) ? (cbih[idx] + cbhh[idx])
                                    : (rbih[idx - 1024] + rbhh[idx - 1024]);
}

// ------------------------------------------------------- P = embed @ Wcat^T
__global__ __launch_bounds__(256) void gemm_p_kernel(
    const float* __restrict__ A,          // embed [50000][300] fp32
    const unsigned short* __restrict__ Bw,// Wcat  [2048][320] bf16
    const float* __restrict__ bias,       // [2048]
    unsigned short* __restrict__ Pout)    // [50000][2048] bf16
{
    const int nb = blockIdx.x * 128;
    const int mb = blockIdx.y * 128;
    const int tid = threadIdx.x;
    const int wv = tid >> 6, ln = tid & 63, l15 = ln & 15, q = ln >> 4;
    const int wm = wv & 1, wn = wv >> 1;

    __shared__ __align__(16) unsigned short At[128][40]; // [m][k] bf16, pad->40

    fvec4 acc[4][4];
    #pragma unroll
    for (int a = 0; a < 4; ++a)
        #pragma unroll
        for (int b = 0; b < 4; ++b) acc[a][b] = (fvec4)0.f;

    for (int kt = 0; kt < 10; ++kt) {
        const int K0 = kt * 32;
        __syncthreads();
        {
            int tr = tid >> 3;   // 0..31
            int tc = tid & 7;    // float4 column
            #pragma unroll
            for (int p = 0; p < 4; ++p) {
                int rrow = tr + p * 32;
                int gr = mb + rrow;
                float4 v = make_float4(0.f, 0.f, 0.f, 0.f);
                if (gr < VOC && (K0 + tc * 4) < EMBD)
                    v = *(const float4*)(A + (size_t)gr * EMBD + K0 + tc * 4);
                ushort4 b;
                b.x = f2bf(v.x); b.y = f2bf(v.y); b.z = f2bf(v.z); b.w = f2bf(v.w);
                *(ushort4*)&At[rrow][tc * 4] = b;
            }
        }
        __syncthreads();
        bf16x8 bf_[4];
        #pragma unroll
        for (int ntt = 0; ntt < 4; ++ntt) {
            int n = nb + wn * 64 + ntt * 16 + l15;
            bf_[ntt] = *(const bf16x8*)(Bw + (size_t)n * 320 + K0 + q * 8);
        }
        #pragma unroll
        for (int mt = 0; mt < 4; ++mt) {
            bf16x8 af = *(const bf16x8*)&At[wm * 64 + mt * 16 + l15][q * 8];
            #pragma unroll
            for (int ntt = 0; ntt < 4; ++ntt)
                acc[mt][ntt] = __builtin_amdgcn_mfma_f32_16x16x32_bf16(
                    af, bf_[ntt], acc[mt][ntt], 0, 0, 0);
        }
    }
    float bv[4];
    #pragma unroll
    for (int ntt = 0; ntt < 4; ++ntt) bv[ntt] = bias[nb + wn * 64 + ntt * 16 + l15];
    #pragma unroll
    for (int mt = 0; mt < 4; ++mt) {
        #pragma unroll
        for (int r = 0; r < 4; ++r) {
            int m = mb + wm * 64 + mt * 16 + q * 4 + r;
            if (m < VOC) {
                size_t base = (size_t)m * 2048 + nb + wn * 64;
                #pragma unroll
                for (int ntt = 0; ntt < 4; ++ntt)
                    Pout[base + ntt * 16 + l15] = f2bf(acc[mt][ntt][r] + bv[ntt]);
            }
        }
    }
}

// ----------------------------------------------------------------- LSTMs
// grid 384 x 1024: blocks [0,128) col, [128,256) row, [256,384) row_neg.
// Block: 32 seqs, 16 waves; wave wv owns hidden units [16wv, 16wv+16).
// Per wave per step: 32 W loads (32KB) + 4 P-DMAs + 2 token loads; 64 MFMA.
// h double-buffered -> one lgkmcnt-only barrier/step.
__global__ __launch_bounds__(1024, 4) void lstm_kernel(
    const int* __restrict__ colTok, const int* __restrict__ rowTok, const int* __restrict__ negTok,
    const int* __restrict__ colLen, const int* __restrict__ rowLen, const int* __restrict__ negLen,
    const unsigned short* __restrict__ P,
    const unsigned short* __restrict__ WhhC, const unsigned short* __restrict__ WhhR,
    float* __restrict__ Hout)
{
    const int part = blockIdx.x >> 7;
    const int sb = blockIdx.x & 127;
    const int s0 = sb * 32;
    const int* tok = part == 0 ? colTok : (part == 1 ? rowTok : negTok);
    const int* len = part == 0 ? colLen : (part == 1 ? rowLen : negLen);
    const unsigned short* Whh = part == 0 ? WhhC : WhhR;
    const int T = part == 0 ? 64 : 16;
    const int pco = part == 0 ? 0 : 1024;
    float* Ho = Hout + (size_t)part * (NSEN * HIDN);

    const int tid = threadIdx.x;
    const int wv = tid >> 6;            // 0..15
    const int ln = tid & 63, l15 = ln & 15, q = ln >> 4;

    __shared__ __align__(16) unsigned short hbf[2][32][256];        // 32 KB
    __shared__ __align__(16) unsigned short pstage[16][4][32][16];  // 64 KB
    char* hB0 = (char*)&hbf[0][0][0];
    char* hB1 = (char*)&hbf[1][0][0];
    const int swz = (l15 & 7) << 4;     // XOR swizzle for h rows

    for (int i = tid; i < 2 * 32 * 256; i += 1024) (&hbf[0][0][0])[i] = 0;

    // lens in regs: per-lane loads + shfl-xor max over the 32 seqs
    const int len0 = len[s0 + l15];
    const int len1 = len[s0 + 16 + l15];
    int ml = max(len0, len1);
    #pragma unroll
    for (int off = 1; off < 16; off <<= 1) ml = max(ml, __shfl_xor(ml, off));
    const int maxlen = ml;

    // per-wave contiguous packed-Whh stream base (32 KB per wave per step)
    const unsigned short* wbase = Whh + (size_t)wv * 16384 + (size_t)ln * 8;

    float c[2][4];
    #pragma unroll
    for (int n = 0; n < 2; ++n)
        #pragma unroll
        for (int r = 0; r < 4; ++r) c[n][r] = 0.f;
    ushort4 hpk[2];
    hpk[0] = make_ushort4(0, 0, 0, 0);
    hpk[1] = make_ushort4(0, 0, 0, 0);

    __syncthreads();   // hbf zero-init visible

    // ---- prologue: DMA-stage P rows for t=0 (per-lane gather source:
    // lane l covers seq l>>1, elem-half l&1 of this wave's 16-unit slice)
    {
        int tcur = tok[(s0 + (ln >> 1)) * T];
        #pragma unroll
        for (int g = 0; g < 4; ++g) {
            const unsigned short* src =
                P + (size_t)tcur * 2048 + pco + g * 256 + wv * 16 + (ln & 1) * 8;
            gld_lds16(src, &pstage[wv][g][0][0]);
        }
    }
    int tknext = tok[(s0 + (ln >> 1)) * T + 1];   // T >= 16

    for (int t = 0; t < maxlen; ++t) {
        const char* hRd = (t & 1) ? hB1 : hB0;
        char* hWr = (t & 1) ? hB0 : hB1;

        // wave-private: wait for this wave's DMAs + token prefetch
        asm volatile("s_waitcnt vmcnt(0)" ::: "memory");

        // acc init from staged P: pstage[wv][g][seq][unit], unit = q*4+r
        fvec4 acc[4][2];  // [gate][nt]
        #pragma unroll
        for (int g = 0; g < 4; ++g)
            #pragma unroll
            for (int nt = 0; nt < 2; ++nt)
                acc[g][nt] = unpk(*(const uint2*)
                    &pstage[wv][g][nt * 16 + l15][q * 4]);

        // gates += Whh_slice * h^T  (contiguous packed frag stream, L2)
        #pragma unroll 2
        for (int kt = 0; kt < 8; ++kt) {
            bf16x8 b0 = *(const bf16x8*)(hRd + l15 * 512 + ((kt * 64 + q * 16) ^ swz));
            bf16x8 b1 = *(const bf16x8*)(hRd + (16 + l15) * 512 + ((kt * 64 + q * 16) ^ swz));
            #pragma unroll
            for (int g = 0; g < 4; ++g) {
                bf16x8 a = *(const bf16x8*)(wbase + (size_t)(kt * 4 + g) * 512);
                acc[g][0] = __builtin_amdgcn_mfma_f32_16x16x32_bf16(a, b0, acc[g][0], 0, 0, 0);
                acc[g][1] = __builtin_amdgcn_mfma_f32_16x16x32_bf16(a, b1, acc[g][1], 0, 0, 0);
            }
        }

        // issue next step's DMAs (wave-private pstage; this wave's pstage
        // ds_reads are complete -- guard with lgkmcnt(0), pinned here).
        // Skip on the last step (wave-uniform branch).
        if (t + 1 < maxlen) {
            __builtin_amdgcn_sched_barrier(0);
            asm volatile("s_waitcnt lgkmcnt(0)" ::: "memory");
            #pragma unroll
            for (int g = 0; g < 4; ++g) {
                const unsigned short* src =
                    P + (size_t)tknext * 2048 + pco + g * 256 + wv * 16 + (ln & 1) * 8;
                gld_lds16(src, &pstage[wv][g][0][0]);
            }
            int t2 = (t + 2 < T) ? (t + 2) : (T - 1);
            tknext = tok[(s0 + (ln >> 1)) * T + t2];
        }

        // activation + h write to the other buffer (frozen lanes rewrite hpk)
        #pragma unroll
        for (int nt = 0; nt < 2; ++nt) {
            bool act = t < (nt ? len1 : len0);
            if (act) {
                float hr[4];
                #pragma unroll
                for (int r = 0; r < 4; ++r) {
                    float iv = acc[0][nt][r];
                    float fv = acc[1][nt][r];
                    float gv = acc[2][nt][r];
                    float ov = acc[3][nt][r];
                    float cn = sigm(fv) * c[nt][r] + sigm(iv) * tanh_(gv);
                    c[nt][r] = cn;
                    hr[r] = sigm(ov) * tanh_(cn);
                }
                hpk[nt] = make_ushort4(f2bf(hr[0]), f2bf(hr[1]),
                                       f2bf(hr[2]), f2bf(hr[3]));
            }
            *(ushort4*)(hWr + (size_t)(nt * 16 + l15) * 512 +
                        ((wv * 32 + q * 8) ^ swz)) = hpk[nt];
        }
        // ONE barrier per step: h writes visible before next step's reads
        asm volatile("s_waitcnt lgkmcnt(0)\n\ts_barrier" ::: "memory");
    }

    const char* hF = (maxlen & 1) ? hB1 : hB0;
    for (int i = tid; i < 32 * HIDN; i += 1024) {
        int sq = i >> 8, hd = i & 255;
        unsigned short hv = *(const unsigned short*)
            (hF + (size_t)sq * 512 + ((hd * 2) ^ ((sq & 7) << 4)));
        Ho[(size_t)(s0 + sq) * HIDN + hd] = bf2f(hv);
    }
}

// ------------------------------------------------------------ segment sum
__global__ void scatter_kernel(const float* __restrict__ Hout,
                               const int* __restrict__ crefs, const int* __restrict__ rrefs,
                               const int* __restrict__ nrefs, float* __restrict__ seg)
{
    int idx = blockIdx.x * 256 + threadIdx.x;       // < 3 * 2^20
    int which = idx >> 20;
    int rem = idx & 1048575;
    int s = rem >> 8, hd = rem & 255;
    const int* refs = which == 0 ? crefs : (which == 1 ? rrefs : nrefs);
    int rf = refs[s];
    atomicAdd(&seg[(size_t)which * 1048576 + (size_t)rf * 256 + hd], Hout[idx]);
}

// ------------------------------------------------------------------ loss
__global__ void loss_kernel(const float* __restrict__ seg, float* __restrict__ part)
{
    int d = blockIdx.x, tid = threadIdx.x;
    const float* sc = seg + (size_t)d * 256;
    const float* sr = seg + 1048576 + (size_t)d * 256;
    const float* sn = seg + 2097152 + (size_t)d * 256;
    float a = sc[tid];
    float p = a * sr[tid];
    float n = a * sn[tid];
    for (int off = 32; off; off >>= 1) { p += __shfl_down(p, off); n += __shfl_down(n, off); }
    __shared__ float rp[4], rn[4];
    if ((tid & 63) == 0) { rp[tid >> 6] = p; rn[tid >> 6] = n; }
    __syncthreads();
    if (tid == 0) {
        float Ps = rp[0] + rp[1] + rp[2] + rp[3];
        float Ns = rn[0] + rn[1] + rn[2] + rn[3];
        float x = Ps - Ns;
        part[d] = fmaxf(-x, 0.f) + log1pf(expf(-fabsf(x)));  // softplus(-x)
    }
}

__global__ void reduce_kernel(const float* __restrict__ part, float* __restrict__ out)
{
    int tid = threadIdx.x;
    float s = 0.f;
    for (int i = tid; i < 4096; i += 256) s += part[i];
    for (int off = 32; off; off >>= 1) s += __shfl_down(s, off);
    __shared__ float r[4];
    if ((tid & 63) == 0) r[tid >> 6] = s;
    __syncthreads();
    if (tid == 0) out[0] = r[0] + r[1] + r[2] + r[3];
}

// ---------------------------------------------------------------------------
extern "C" void kernel_launch(void* const* d_in, const int* in_sizes, int n_in,
                              void* d_out, int out_size, void* d_ws, size_t ws_size,
                              hipStream_t stream)
{
    const int*   col      = (const int*)d_in[0];
    const int*   row      = (const int*)d_in[1];
    const int*   rneg     = (const int*)d_in[2];
    const int*   col_lens = (const int*)d_in[3];
    const int*   row_lens = (const int*)d_in[4];
    const int*   rng_lens = (const int*)d_in[5];
    const int*   col_refs = (const int*)d_in[6];
    const int*   row_refs = (const int*)d_in[7];
    const int*   rng_refs = (const int*)d_in[8];
    const float* embed    = (const float*)d_in[9];
    const float* cWih     = (const float*)d_in[10];
    const float* cWhh     = (const float*)d_in[11];
    const float* cbih     = (const float*)d_in[12];
    const float* cbhh     = (const float*)d_in[13];
    const float* rWih     = (const float*)d_in[14];
    const float* rWhh     = (const float*)d_in[15];
    const float* rbih     = (const float*)d_in[16];
    const float* rbhh     = (const float*)d_in[17];

    char* ws = (char*)d_ws;
    unsigned short* P    = (unsigned short*)(ws + OFF_P);
    unsigned short* Wcat = (unsigned short*)(ws + OFF_WCAT);
    unsigned short* WhhC = (unsigned short*)(ws + OFF_WHHC);
    unsigned short* WhhR = (unsigned short*)(ws + OFF_WHHR);
    float* biascat = (float*)(ws + OFF_BIAS);
    float* Hbuf    = (float*)(ws + OFF_H);
    float* seg     = (float*)(ws + OFF_SEG);
    float* lpart   = (float*)(ws + OFF_LOSS);

    hipMemsetAsync(seg, 0, 3 * 4096 * 256 * sizeof(float), stream);

    prep_kernel<<<4616, 256, 0, stream>>>(cWih, rWih, cWhh, rWhh,
                                          cbih, cbhh, rbih, rbhh,
                                          Wcat, WhhC, WhhR, biascat);
    gemm_p_kernel<<<dim3(16, 391), 256, 0, stream>>>(embed, Wcat, biascat, P);
    lstm_kernel<<<384, 1024, 0, stream>>>(col, row, rneg,
                                          col_lens, row_lens, rng_lens,
                                          P, WhhC, WhhR, Hbuf);
    scatter_kernel<<<12288, 256, 0, stream>>>(Hbuf, col_refs, row_refs, rng_refs, seg);
    loss_kernel<<<4096, 256, 0, stream>>>(seg, lpart);
    reduce_kernel<<<1, 256, 0, stream>>>(lpart, (float*)d_out);
}